// Round 1
// baseline (197.779 us; speedup 1.0000x reference)
//
#include <hip/hip_runtime.h>
#include <hip/hip_bf16.h>

// ScatterRouter: N=8192 tokens, E=8 experts, K=2, D=2048 (fp32 rows).
// Output layout (float32, concatenated): out_data[N*K][D], out_tags[N*K], counts[E].
// Position of (token n, expert e) = expert_base[e] + #{n' < n : e in top2(n')}.

#define EXPERTS 8
#define TOPK 2
#define BLK 256

// ---------------- Kernel 1: top-2 mask + per-block per-expert counts ----------------
__global__ void k_mask_count(const float* __restrict__ gates,
                             int* __restrict__ masks,
                             int* __restrict__ block_counts) {
    int n = blockIdx.x * BLK + threadIdx.x;
    const float4* g4 = (const float4*)(gates + (size_t)n * EXPERTS);
    float4 a = g4[0], b = g4[1];
    float v[EXPERTS] = {a.x, a.y, a.z, a.w, b.x, b.y, b.z, b.w};

    // argmax with strict > keeps lowest index on ties (matches lax.top_k)
    int e1 = 0; float b1 = v[0];
    #pragma unroll
    for (int e = 1; e < EXPERTS; e++) if (v[e] > b1) { b1 = v[e]; e1 = e; }
    int e2 = -1; float b2 = -1e30f;
    #pragma unroll
    for (int e = 0; e < EXPERTS; e++) if (e != e1 && v[e] > b2) { b2 = v[e]; e2 = e; }

    int mask = (1 << e1) | (1 << e2);
    masks[n] = mask;

    int wave = threadIdx.x >> 6;
    int lane = threadIdx.x & 63;
    __shared__ int wc[BLK / 64][EXPERTS];
    #pragma unroll
    for (int e = 0; e < EXPERTS; e++) {
        unsigned long long bal = __ballot((mask >> e) & 1);
        if (lane == 0) wc[wave][e] = __popcll(bal);
    }
    __syncthreads();
    if (threadIdx.x < EXPERTS) {
        int e = threadIdx.x;
        int t = 0;
        #pragma unroll
        for (int w = 0; w < BLK / 64; w++) t += wc[w][e];
        block_counts[blockIdx.x * EXPERTS + e] = t;
    }
}

// ---------------- Kernel 2: scan block counts -> offsets + counts output ----------------
__global__ void k_scan(const int* __restrict__ block_counts,
                       int* __restrict__ block_offsets,
                       float* __restrict__ counts_out, int NB) {
    __shared__ int tot[EXPERTS];
    __shared__ int base[EXPERTS];
    int e = threadIdx.x;
    if (e < EXPERTS) {
        int t = 0;
        for (int b = 0; b < NB; b++) t += block_counts[b * EXPERTS + e];
        tot[e] = t;
        counts_out[e] = (float)t;
    }
    __syncthreads();
    if (threadIdx.x == 0) {
        int acc = 0;
        for (int i = 0; i < EXPERTS; i++) { base[i] = acc; acc += tot[i]; }
    }
    __syncthreads();
    if (e < EXPERTS) {
        int acc = base[e];
        for (int b = 0; b < NB; b++) {
            block_offsets[b * EXPERTS + e] = acc;
            acc += block_counts[b * EXPERTS + e];
        }
    }
}

// ---------------- Kernel 3: per-token global rank -> tok_of_pos ----------------
__global__ void k_pos(const int* __restrict__ masks,
                      const int* __restrict__ block_offsets,
                      int* __restrict__ tok_of_pos) {
    int n = blockIdx.x * BLK + threadIdx.x;
    int mask = masks[n];
    int wave = threadIdx.x >> 6;
    int lane = threadIdx.x & 63;
    __shared__ int wc[BLK / 64][EXPERTS];
    unsigned long long bal[EXPERTS];
    #pragma unroll
    for (int e = 0; e < EXPERTS; e++) {
        bal[e] = __ballot((mask >> e) & 1);
        if (lane == 0) wc[wave][e] = __popcll(bal[e]);
    }
    __syncthreads();
    unsigned long long below = (lane == 0) ? 0ull : ((~0ull) >> (64 - lane));
    #pragma unroll
    for (int e = 0; e < EXPERTS; e++) {
        if ((mask >> e) & 1) {
            int wbase = 0;
            for (int w = 0; w < wave; w++) wbase += wc[w][e];
            int r = __popcll(bal[e] & below);
            int pos = block_offsets[blockIdx.x * EXPERTS + e] + wbase + r;
            tok_of_pos[pos] = n;
        }
    }
}

// ---------------- Kernel 4: row copy (one block per output row) ----------------
__global__ void k_copy(const float* __restrict__ in_flow,
                       const int* __restrict__ tok_of_pos,
                       float* __restrict__ out_data,
                       float* __restrict__ out_tags, int D) {
    int p = blockIdx.x;
    int tok = tok_of_pos[p];
    if (threadIdx.x == 0) out_tags[p] = (float)tok;
    const float4* src = (const float4*)(in_flow + (size_t)tok * D);
    float4* dst = (float4*)(out_data + (size_t)p * D);
    int nv = D >> 2;  // float4s per row
    for (int i = threadIdx.x; i < nv; i += BLK) dst[i] = src[i];
}

extern "C" void kernel_launch(void* const* d_in, const int* in_sizes, int n_in,
                              void* d_out, int out_size, void* d_ws, size_t ws_size,
                              hipStream_t stream) {
    const float* in_flow = (const float*)d_in[0];
    const float* gates   = (const float*)d_in[1];

    const int N  = in_sizes[1] / EXPERTS;      // 8192
    const int D  = in_sizes[0] / N;            // 2048
    const int NB = (N + BLK - 1) / BLK;        // 32
    const int NK = N * TOPK;                   // 16384

    // Workspace layout (ints)
    int* masks         = (int*)d_ws;
    int* block_counts  = masks + N;
    int* block_offsets = block_counts + NB * EXPERTS;
    int* tok_of_pos    = block_offsets + NB * EXPERTS;

    // Output layout (floats)
    float* out_data  = (float*)d_out;
    float* out_tags  = out_data + (size_t)NK * D;
    float* counts_out = out_tags + NK;

    hipLaunchKernelGGL(k_mask_count, dim3(NB), dim3(BLK), 0, stream,
                       gates, masks, block_counts);
    hipLaunchKernelGGL(k_scan, dim3(1), dim3(64), 0, stream,
                       block_counts, block_offsets, counts_out, NB);
    hipLaunchKernelGGL(k_pos, dim3(NB), dim3(BLK), 0, stream,
                       masks, block_offsets, tok_of_pos);
    hipLaunchKernelGGL(k_copy, dim3(NK), dim3(BLK), 0, stream,
                       in_flow, tok_of_pos, out_data, out_tags, D);
}